// Round 2
// baseline (238.755 us; speedup 1.0000x reference)
//
#include <hip/hip_runtime.h>
#include <math.h>

#define N_HID 128
#define E_PER_REL 200000
#define GROUPS_PER_REL 20000      // 8-lane groups per relation
#define EDGES_PER_GROUP 10        // 20000 * 10 = 200000 exactly
#define THREADS 256

// 8 lanes per edge: each lane holds 16 dims (4 x float4) of h[src], h[dst].
// W row is block-uniform (rel = blockIdx.y) and loaded once into registers.
// Each 8-lane group loops over 10 edges strided by GROUPS_PER_REL so that
// index loads and output stores stay coalesced across the wave.
__global__ __launch_bounds__(THREADS) void distmult_kernel(
    const float* __restrict__ h,
    const float* __restrict__ W,
    const int* __restrict__ src_idx,
    const int* __restrict__ dst_idx,
    float* __restrict__ out)
{
    const int lane8 = threadIdx.x & 7;
    const int group = (blockIdx.x * THREADS + threadIdx.x) >> 3;  // 0..19999
    const int rel   = blockIdx.y;

    // W row: 8 lanes x 4 float4 = 512 B, L1/L2-hot, loaded once.
    const float4* wr = (const float4*)(W + rel * N_HID);
    const float4 w0 = wr[lane8];
    const float4 w1 = wr[lane8 + 8];
    const float4 w2 = wr[lane8 + 16];
    const float4 w3 = wr[lane8 + 24];

    int e = rel * E_PER_REL + group;

    #pragma unroll 2
    for (int k = 0; k < EDGES_PER_GROUP; ++k, e += GROUPS_PER_REL) {
        const int s = src_idx[e];   // broadcast within the 8-lane group
        const int d = dst_idx[e];

        const float4* hu = (const float4*)(h + (size_t)s * N_HID);
        const float4* hv = (const float4*)(h + (size_t)d * N_HID);

        const float4 u0 = hu[lane8];
        const float4 u1 = hu[lane8 + 8];
        const float4 u2 = hu[lane8 + 16];
        const float4 u3 = hu[lane8 + 24];
        const float4 v0 = hv[lane8];
        const float4 v1 = hv[lane8 + 8];
        const float4 v2 = hv[lane8 + 16];
        const float4 v3 = hv[lane8 + 24];

        float p;
        p  = (u0.x * v0.x) * w0.x;
        p += (u0.y * v0.y) * w0.y;
        p += (u0.z * v0.z) * w0.z;
        p += (u0.w * v0.w) * w0.w;
        p += (u1.x * v1.x) * w1.x;
        p += (u1.y * v1.y) * w1.y;
        p += (u1.z * v1.z) * w1.z;
        p += (u1.w * v1.w) * w1.w;
        p += (u2.x * v2.x) * w2.x;
        p += (u2.y * v2.y) * w2.y;
        p += (u2.z * v2.z) * w2.z;
        p += (u2.w * v2.w) * w2.w;
        p += (u3.x * v3.x) * w3.x;
        p += (u3.y * v3.y) * w3.y;
        p += (u3.z * v3.z) * w3.z;
        p += (u3.w * v3.w) * w3.w;

        // reduce across the 8-lane group (xor masks 1,2,4 stay in-group)
        p += __shfl_xor(p, 1);
        p += __shfl_xor(p, 2);
        p += __shfl_xor(p, 4);

        if (lane8 == 0) {
            out[e] = 1.0f / (1.0f + __expf(-p));
        }
    }
}

extern "C" void kernel_launch(void* const* d_in, const int* in_sizes, int n_in,
                              void* d_out, int out_size, void* d_ws, size_t ws_size,
                              hipStream_t stream) {
    const float* h       = (const float*)d_in[0];
    const float* W       = (const float*)d_in[1];
    const int*   src_idx = (const int*)d_in[2];
    const int*   dst_idx = (const int*)d_in[3];
    float*       out     = (float*)d_out;

    // 20000 groups/rel * 8 lanes = 160000 threads/rel = 625 blocks of 256
    dim3 grid(GROUPS_PER_REL * 8 / THREADS, 6, 1);
    distmult_kernel<<<grid, THREADS, 0, stream>>>(h, W, src_idx, dst_idx, out);
}

// Round 3
// 169.690 us; speedup vs baseline: 1.4070x; 1.4070x over previous
//
#include <hip/hip_runtime.h>
#include <hip/hip_fp16.h>
#include <math.h>

#define N_NODES 100000
#define N_HID 128
#define E_PER_REL 200000
#define GROUPS_PER_REL 20000      // 8-lane groups per relation
#define EDGES_PER_GROUP 10        // 20000 * 10 = 200000 exactly
#define THREADS 256

// ---------------- pass 1: h (fp32) -> h16 (fp16) in workspace ----------------
// one thread per 8 elements: 2x float4 load, 1x 16B store
__global__ __launch_bounds__(THREADS) void convert_h_kernel(
    const float* __restrict__ h, __half* __restrict__ h16, int n8)
{
    int i = blockIdx.x * blockDim.x + threadIdx.x;
    if (i >= n8) return;
    const float4* src = (const float4*)h;
    float4 a = src[2 * i];
    float4 b = src[2 * i + 1];
    __half2 r[4];
    r[0] = __floats2half2_rn(a.x, a.y);
    r[1] = __floats2half2_rn(a.z, a.w);
    r[2] = __floats2half2_rn(b.x, b.y);
    r[3] = __floats2half2_rn(b.z, b.w);
    ((float4*)h16)[i] = *(float4*)r;
}

// ---------------- pass 2: gather h16 rows (256B), dot, sigmoid ---------------
// 8 lanes per edge, each lane covers 16 dims = two 16B (8-half) loads.
// W row (fp32, cache-hot) is block-uniform; accumulate in fp32.
__global__ __launch_bounds__(THREADS) void distmult_fp16_kernel(
    const __half* __restrict__ h16,
    const float* __restrict__ W,
    const int* __restrict__ src_idx,
    const int* __restrict__ dst_idx,
    float* __restrict__ out)
{
    const int lane8 = threadIdx.x & 7;
    const int group = (blockIdx.x * THREADS + threadIdx.x) >> 3;  // 0..19999
    const int rel   = blockIdx.y;

    // W: lane8 covers dims [8*lane8, 8*lane8+8) and [64+8*lane8, ...)
    const float4* wr4 = (const float4*)(W + rel * N_HID);
    const float4 wa0 = wr4[2 * lane8];
    const float4 wa1 = wr4[2 * lane8 + 1];
    const float4 wb0 = wr4[16 + 2 * lane8];
    const float4 wb1 = wr4[16 + 2 * lane8 + 1];

    int e = rel * E_PER_REL + group;

    #pragma unroll 2
    for (int k = 0; k < EDGES_PER_GROUP; ++k, e += GROUPS_PER_REL) {
        const int s = src_idx[e];   // broadcast within the 8-lane group
        const int d = dst_idx[e];

        const float4* hu = (const float4*)(h16 + (size_t)s * N_HID);
        const float4* hv = (const float4*)(h16 + (size_t)d * N_HID);

        float4 u0raw = hu[lane8];       // dims 8*lane8 .. +8
        float4 u1raw = hu[lane8 + 8];   // dims 64+8*lane8 .. +8
        float4 v0raw = hv[lane8];
        float4 v1raw = hv[lane8 + 8];

        const __half2* u0 = (const __half2*)&u0raw;
        const __half2* u1 = (const __half2*)&u1raw;
        const __half2* v0 = (const __half2*)&v0raw;
        const __half2* v1 = (const __half2*)&v1raw;
        const float*   wa = (const float*)&wa0;  // wa0,wa1 contiguous? not guaranteed
        // use explicit arrays instead:
        float wlo[8] = {wa0.x, wa0.y, wa0.z, wa0.w, wa1.x, wa1.y, wa1.z, wa1.w};
        float whi[8] = {wb0.x, wb0.y, wb0.z, wb0.w, wb1.x, wb1.y, wb1.z, wb1.w};
        (void)wa;

        float p = 0.0f;
        #pragma unroll
        for (int j = 0; j < 4; ++j) {
            float2 uu = __half22float2(u0[j]);
            float2 vv = __half22float2(v0[j]);
            p += uu.x * vv.x * wlo[2 * j];
            p += uu.y * vv.y * wlo[2 * j + 1];
        }
        #pragma unroll
        for (int j = 0; j < 4; ++j) {
            float2 uu = __half22float2(u1[j]);
            float2 vv = __half22float2(v1[j]);
            p += uu.x * vv.x * whi[2 * j];
            p += uu.y * vv.y * whi[2 * j + 1];
        }

        // reduce across the 8-lane group
        p += __shfl_xor(p, 1);
        p += __shfl_xor(p, 2);
        p += __shfl_xor(p, 4);

        if (lane8 == 0) {
            out[e] = 1.0f / (1.0f + __expf(-p));
        }
    }
}

// ---------------- fallback: fp32 gather (R2 kernel) --------------------------
__global__ __launch_bounds__(THREADS) void distmult_fp32_kernel(
    const float* __restrict__ h,
    const float* __restrict__ W,
    const int* __restrict__ src_idx,
    const int* __restrict__ dst_idx,
    float* __restrict__ out)
{
    const int lane8 = threadIdx.x & 7;
    const int group = (blockIdx.x * THREADS + threadIdx.x) >> 3;
    const int rel   = blockIdx.y;

    const float4* wr = (const float4*)(W + rel * N_HID);
    const float4 w0 = wr[lane8];
    const float4 w1 = wr[lane8 + 8];
    const float4 w2 = wr[lane8 + 16];
    const float4 w3 = wr[lane8 + 24];

    int e = rel * E_PER_REL + group;

    #pragma unroll 2
    for (int k = 0; k < EDGES_PER_GROUP; ++k, e += GROUPS_PER_REL) {
        const int s = src_idx[e];
        const int d = dst_idx[e];
        const float4* hu = (const float4*)(h + (size_t)s * N_HID);
        const float4* hv = (const float4*)(h + (size_t)d * N_HID);
        const float4 u0 = hu[lane8],      v0 = hv[lane8];
        const float4 u1 = hu[lane8 + 8],  v1 = hv[lane8 + 8];
        const float4 u2 = hu[lane8 + 16], v2 = hv[lane8 + 16];
        const float4 u3 = hu[lane8 + 24], v3 = hv[lane8 + 24];

        float p;
        p  = (u0.x * v0.x) * w0.x + (u0.y * v0.y) * w0.y + (u0.z * v0.z) * w0.z + (u0.w * v0.w) * w0.w;
        p += (u1.x * v1.x) * w1.x + (u1.y * v1.y) * w1.y + (u1.z * v1.z) * w1.z + (u1.w * v1.w) * w1.w;
        p += (u2.x * v2.x) * w2.x + (u2.y * v2.y) * w2.y + (u2.z * v2.z) * w2.z + (u2.w * v2.w) * w2.w;
        p += (u3.x * v3.x) * w3.x + (u3.y * v3.y) * w3.y + (u3.z * v3.z) * w3.z + (u3.w * v3.w) * w3.w;

        p += __shfl_xor(p, 1);
        p += __shfl_xor(p, 2);
        p += __shfl_xor(p, 4);

        if (lane8 == 0) out[e] = 1.0f / (1.0f + __expf(-p));
    }
}

extern "C" void kernel_launch(void* const* d_in, const int* in_sizes, int n_in,
                              void* d_out, int out_size, void* d_ws, size_t ws_size,
                              hipStream_t stream) {
    const float* h       = (const float*)d_in[0];
    const float* W       = (const float*)d_in[1];
    const int*   src_idx = (const int*)d_in[2];
    const int*   dst_idx = (const int*)d_in[3];
    float*       out     = (float*)d_out;

    const size_t need = (size_t)N_NODES * N_HID * sizeof(__half);  // 25.6 MB
    dim3 grid(GROUPS_PER_REL * 8 / THREADS, 6, 1);

    if (ws_size >= need) {
        __half* h16 = (__half*)d_ws;
        const int n8 = N_NODES * N_HID / 8;  // 1.6M
        convert_h_kernel<<<(n8 + THREADS - 1) / THREADS, THREADS, 0, stream>>>(h, h16, n8);
        distmult_fp16_kernel<<<grid, THREADS, 0, stream>>>(h16, W, src_idx, dst_idx, out);
    } else {
        distmult_fp32_kernel<<<grid, THREADS, 0, stream>>>(h, W, src_idx, dst_idx, out);
    }
}

// Round 4
// 167.712 us; speedup vs baseline: 1.4236x; 1.0118x over previous
//
#include <hip/hip_runtime.h>
#include <hip/hip_fp16.h>
#include <math.h>

#define N_NODES 100000
#define N_HID 128
#define E_PER_REL 200000
#define EDGES_PER_GROUP 2
#define GROUPS_PER_REL (E_PER_REL / EDGES_PER_GROUP)   // 100000
#define THREADS 256

// ---------------- pass 1: h (fp32) -> h16 (fp16) in workspace ----------------
// one thread per 16 elements: 4x float4 load, 2x 16B store
__global__ __launch_bounds__(THREADS) void convert_h_kernel(
    const float* __restrict__ h, __half* __restrict__ h16, int n16)
{
    int i = blockIdx.x * blockDim.x + threadIdx.x;
    if (i >= n16) return;
    const float4* src = (const float4*)h;
    float4* dst = (float4*)h16;
    #pragma unroll
    for (int half = 0; half < 2; ++half) {
        float4 a = src[4 * i + 2 * half];
        float4 b = src[4 * i + 2 * half + 1];
        __half2 r[4];
        r[0] = __floats2half2_rn(a.x, a.y);
        r[1] = __floats2half2_rn(a.z, a.w);
        r[2] = __floats2half2_rn(b.x, b.y);
        r[3] = __floats2half2_rn(b.z, b.w);
        dst[2 * i + half] = *(float4*)r;
    }
}

// ---------------- pass 2: gather h16 rows (256B), dot, sigmoid ---------------
// 8 lanes per edge, each lane covers 16 dims = two 16B (8-half) loads.
// W row (fp32, cache-hot) is block-uniform; accumulate in fp32.
// EDGES_PER_GROUP=2 -> 18750 blocks for fine-grained load balancing (the
// random-gather latency skew makes coarse 10-edge loops produce stragglers:
// R3 measured Occupancy 68% vs 85% with a fine grid).
__global__ __launch_bounds__(THREADS) void distmult_fp16_kernel(
    const __half* __restrict__ h16,
    const float* __restrict__ W,
    const int* __restrict__ src_idx,
    const int* __restrict__ dst_idx,
    float* __restrict__ out)
{
    const int lane8 = threadIdx.x & 7;
    const int group = (blockIdx.x * THREADS + threadIdx.x) >> 3;  // 0..GROUPS_PER_REL-1
    const int rel   = blockIdx.y;

    // W: lane8 covers dims [8*lane8, 8*lane8+8) and [64+8*lane8, ...)
    const float4* wr4 = (const float4*)(W + rel * N_HID);
    const float4 wa0 = wr4[2 * lane8];
    const float4 wa1 = wr4[2 * lane8 + 1];
    const float4 wb0 = wr4[16 + 2 * lane8];
    const float4 wb1 = wr4[16 + 2 * lane8 + 1];

    const float wlo[8] = {wa0.x, wa0.y, wa0.z, wa0.w, wa1.x, wa1.y, wa1.z, wa1.w};
    const float whi[8] = {wb0.x, wb0.y, wb0.z, wb0.w, wb1.x, wb1.y, wb1.z, wb1.w};

    int e = rel * E_PER_REL + group;

    #pragma unroll
    for (int k = 0; k < EDGES_PER_GROUP; ++k, e += GROUPS_PER_REL) {
        const int s = src_idx[e];   // broadcast within the 8-lane group
        const int d = dst_idx[e];

        const float4* hu = (const float4*)(h16 + (size_t)s * N_HID);
        const float4* hv = (const float4*)(h16 + (size_t)d * N_HID);

        float4 u0raw = hu[lane8];       // dims 8*lane8 .. +8
        float4 u1raw = hu[lane8 + 8];   // dims 64+8*lane8 .. +8
        float4 v0raw = hv[lane8];
        float4 v1raw = hv[lane8 + 8];

        const __half2* u0 = (const __half2*)&u0raw;
        const __half2* u1 = (const __half2*)&u1raw;
        const __half2* v0 = (const __half2*)&v0raw;
        const __half2* v1 = (const __half2*)&v1raw;

        float p = 0.0f;
        #pragma unroll
        for (int j = 0; j < 4; ++j) {
            float2 uu = __half22float2(u0[j]);
            float2 vv = __half22float2(v0[j]);
            p += uu.x * vv.x * wlo[2 * j];
            p += uu.y * vv.y * wlo[2 * j + 1];
        }
        #pragma unroll
        for (int j = 0; j < 4; ++j) {
            float2 uu = __half22float2(u1[j]);
            float2 vv = __half22float2(v1[j]);
            p += uu.x * vv.x * whi[2 * j];
            p += uu.y * vv.y * whi[2 * j + 1];
        }

        // reduce across the 8-lane group
        p += __shfl_xor(p, 1);
        p += __shfl_xor(p, 2);
        p += __shfl_xor(p, 4);

        if (lane8 == 0) {
            out[e] = 1.0f / (1.0f + __expf(-p));
        }
    }
}

// ---------------- fallback: fp32 gather (R2 kernel) --------------------------
__global__ __launch_bounds__(THREADS) void distmult_fp32_kernel(
    const float* __restrict__ h,
    const float* __restrict__ W,
    const int* __restrict__ src_idx,
    const int* __restrict__ dst_idx,
    float* __restrict__ out)
{
    const int lane8 = threadIdx.x & 7;
    const int group = (blockIdx.x * THREADS + threadIdx.x) >> 3;
    const int rel   = blockIdx.y;

    const float4* wr = (const float4*)(W + rel * N_HID);
    const float4 w0 = wr[lane8];
    const float4 w1 = wr[lane8 + 8];
    const float4 w2 = wr[lane8 + 16];
    const float4 w3 = wr[lane8 + 24];

    int e = rel * E_PER_REL + group;

    #pragma unroll
    for (int k = 0; k < EDGES_PER_GROUP; ++k, e += GROUPS_PER_REL) {
        const int s = src_idx[e];
        const int d = dst_idx[e];
        const float4* hu = (const float4*)(h + (size_t)s * N_HID);
        const float4* hv = (const float4*)(h + (size_t)d * N_HID);
        const float4 u0 = hu[lane8],      v0 = hv[lane8];
        const float4 u1 = hu[lane8 + 8],  v1 = hv[lane8 + 8];
        const float4 u2 = hu[lane8 + 16], v2 = hv[lane8 + 16];
        const float4 u3 = hu[lane8 + 24], v3 = hv[lane8 + 24];

        float p;
        p  = (u0.x * v0.x) * w0.x + (u0.y * v0.y) * w0.y + (u0.z * v0.z) * w0.z + (u0.w * v0.w) * w0.w;
        p += (u1.x * v1.x) * w1.x + (u1.y * v1.y) * w1.y + (u1.z * v1.z) * w1.z + (u1.w * v1.w) * w1.w;
        p += (u2.x * v2.x) * w2.x + (u2.y * v2.y) * w2.y + (u2.z * v2.z) * w2.z + (u2.w * v2.w) * w2.w;
        p += (u3.x * v3.x) * w3.x + (u3.y * v3.y) * w3.y + (u3.z * v3.z) * w3.z + (u3.w * v3.w) * w3.w;

        p += __shfl_xor(p, 1);
        p += __shfl_xor(p, 2);
        p += __shfl_xor(p, 4);

        if (lane8 == 0) out[e] = 1.0f / (1.0f + __expf(-p));
    }
}

extern "C" void kernel_launch(void* const* d_in, const int* in_sizes, int n_in,
                              void* d_out, int out_size, void* d_ws, size_t ws_size,
                              hipStream_t stream) {
    const float* h       = (const float*)d_in[0];
    const float* W       = (const float*)d_in[1];
    const int*   src_idx = (const int*)d_in[2];
    const int*   dst_idx = (const int*)d_in[3];
    float*       out     = (float*)d_out;

    const size_t need = (size_t)N_NODES * N_HID * sizeof(__half);  // 25.6 MB
    dim3 grid(GROUPS_PER_REL * 8 / THREADS, 6, 1);                 // 3125 x 6

    if (ws_size >= need) {
        __half* h16 = (__half*)d_ws;
        const int n16 = N_NODES * N_HID / 16;  // 800k threads
        convert_h_kernel<<<(n16 + THREADS - 1) / THREADS, THREADS, 0, stream>>>(h, h16, n16);
        distmult_fp16_kernel<<<grid, THREADS, 0, stream>>>(h16, W, src_idx, dst_idx, out);
    } else {
        distmult_fp32_kernel<<<grid, THREADS, 0, stream>>>(h, W, src_idx, dst_idx, out);
    }
}